// Round 10
// baseline (9943.494 us; speedup 1.0000x reference)
//
#include <hip/hip_runtime.h>
#include <hip/hip_bf16.h>
#include <hip/hip_cooperative_groups.h>

namespace cg = cooperative_groups;

#define Bn 64
#define Sn 256
#define Cn 512
#define Hn 1024
#define On 1024
#define NL 3

// ------------------------------------------------------------------
// prep: h0T[l][k][b] = hid[b][l+1][k]  (64x64 LDS tile transpose)
// ------------------------------------------------------------------
__global__ __launch_bounds__(256) void prep_kernel(const float* __restrict__ hid,
                                                   float* __restrict__ h0T) {
    __shared__ float T[64][65];
    int l = blockIdx.x >> 4;
    int kb = (blockIdx.x & 15) * 64;
    int tid = threadIdx.x;
    for (int e = tid; e < 1024; e += 256) {
        int b = e >> 4, k4 = (e & 15) * 4;
        float4 v = *(const float4*)&hid[(size_t)b * 4096 + (size_t)(l + 1) * 1024 + kb + k4];
        T[b][k4] = v.x; T[b][k4 + 1] = v.y; T[b][k4 + 2] = v.z; T[b][k4 + 3] = v.w;
    }
    __syncthreads();
    for (int e = tid; e < 1024; e += 256) {
        int k = e >> 4, b4 = (e & 15) * 4;
        float4 v = make_float4(T[b4][k], T[b4 + 1][k], T[b4 + 2][k], T[b4 + 3][k]);
        *(float4*)&h0T[(size_t)l * 65536 + (size_t)(kb + k) * 64 + b4] = v;
    }
}

// ------------------------------------------------------------------
// G1: h0proj[b][g] = fc1_b[g] + sum_h h0[b][h] * fc1_w[g][512+h]
// ------------------------------------------------------------------
__global__ __launch_bounds__(256) void g1_kernel(const float* __restrict__ hid,
                                                 const float* __restrict__ fc1_w,
                                                 const float* __restrict__ fc1_b,
                                                 float* __restrict__ h0proj) {
    __shared__ __align__(16) float h0s[Hn];
    int b = blockIdx.x;
    int tid = threadIdx.x;
    for (int i = tid; i < Hn; i += 256) h0s[i] = hid[(size_t)b * 4 * Hn + i];
    __syncthreads();
    for (int g = tid; g < Hn; g += 256) {
        const float* wr = fc1_w + (size_t)g * (Cn + Hn) + Cn;
        float acc = 0.f;
        for (int k = 0; k < Hn; k += 4) {
            float4 w4 = *(const float4*)&wr[k];
            acc = fmaf(w4.x, h0s[k + 0], acc);
            acc = fmaf(w4.y, h0s[k + 1], acc);
            acc = fmaf(w4.z, h0s[k + 2], acc);
            acc = fmaf(w4.w, h0s[k + 3], acc);
        }
        h0proj[b * Hn + g] = acc + fc1_b[g];
    }
}

// ------------------------------------------------------------------
// G2: tb[t][g][b] = bf16( tanh( X[t,b,:512]@fc1_w[g,:512] + h0proj[b][g] ) )
// ------------------------------------------------------------------
__global__ __launch_bounds__(256) void g2_kernel(const float* __restrict__ x,
                                                 const float* __restrict__ fc1_w,
                                                 const float* __restrict__ h0proj,
                                                 __hip_bfloat16* __restrict__ tb) {
    __shared__ __align__(16) float As[64][64];
    __shared__ __align__(16) float Bs[64][64];
    int tid = threadIdx.x;
    int bx = blockIdx.x;
    int g0 = blockIdx.y * 64;
    int ml = tid & 63;
    int kq = tid >> 6;
    const float* xrow = x + (size_t)ml * (Sn * Cn) + (size_t)bx * Cn;
    const float* wrow = fc1_w + (size_t)(g0 + ml) * (Cn + Hn);
    int wave = tid >> 6, lane = tid & 63;
    int tm = (wave & 1) * 32 + (lane & 7) * 4;
    int tg = (wave >> 1) * 32 + (lane >> 3) * 4;
    float acc[4][4] = {};
    for (int kc = 0; kc < Cn / 64; ++kc) {
#pragma unroll
        for (int r = 0; r < 4; ++r) {
            int kk = kq * 16 + r * 4;
            float4 v = *(const float4*)&xrow[kc * 64 + kk];
            As[kk + 0][ml] = v.x; As[kk + 1][ml] = v.y;
            As[kk + 2][ml] = v.z; As[kk + 3][ml] = v.w;
        }
#pragma unroll
        for (int r = 0; r < 4; ++r) {
            int kk = kq * 16 + r * 4;
            float4 v = *(const float4*)&wrow[kc * 64 + kk];
            Bs[kk + 0][ml] = v.x; Bs[kk + 1][ml] = v.y;
            Bs[kk + 2][ml] = v.z; Bs[kk + 3][ml] = v.w;
        }
        __syncthreads();
#pragma unroll 4
        for (int k = 0; k < 64; ++k) {
            float4 a4 = *(const float4*)&As[k][tm];
            float4 b4 = *(const float4*)&Bs[k][tg];
            float av[4] = {a4.x, a4.y, a4.z, a4.w};
            float bv[4] = {b4.x, b4.y, b4.z, b4.w};
#pragma unroll
            for (int i = 0; i < 4; ++i)
#pragma unroll
                for (int j = 0; j < 4; ++j)
                    acc[i][j] = fmaf(av[i], bv[j], acc[i][j]);
        }
        __syncthreads();
    }
#pragma unroll
    for (int j = 0; j < 4; ++j) {
        int g = g0 + tg + j;
        union { ushort4 u4; __hip_bfloat16 h[4]; } cv;
#pragma unroll
        for (int i = 0; i < 4; ++i) {
            float hp = h0proj[(size_t)(tm + i) * Hn + g];
            cv.h[i] = __float2bfloat16(tanhf(acc[i][j] + hp));
        }
        *(ushort4*)&tb[((size_t)bx * Hn + g) * 64 + tm] = cv.u4;
    }
}

// ------------------------------------------------------------------
// G3: logits[m][o] = relu( temp[m][:] @ fc2_w[o][:] + fc2_b[o] )
// ------------------------------------------------------------------
__global__ __launch_bounds__(256) void g3_kernel(const __hip_bfloat16* __restrict__ tb,
                                                 const float* __restrict__ fc2_w,
                                                 const float* __restrict__ fc2_b,
                                                 float* __restrict__ logits) {
    __shared__ __align__(16) float As[64][64];
    __shared__ __align__(16) float Bs[64][64];
    int tid = threadIdx.x;
    int bx = blockIdx.x;
    int g0 = blockIdx.y * 64;
    int ml = tid & 63;
    int kq = tid >> 6;
    const float* wrow = fc2_w + (size_t)(g0 + ml) * Hn;
    int wave = tid >> 6, lane = tid & 63;
    int tm = (wave & 1) * 32 + (lane & 7) * 4;
    int tg = (wave >> 1) * 32 + (lane >> 3) * 4;
    float acc[4][4] = {};
    for (int kc = 0; kc < Hn / 64; ++kc) {
        for (int e = tid; e < 4096; e += 256) {
            int kk = e >> 6, mm = e & 63;
            As[kk][mm] = __bfloat162float(tb[((size_t)bx * Hn + kc * 64 + kk) * 64 + mm]);
        }
#pragma unroll
        for (int r = 0; r < 4; ++r) {
            int kk = kq * 16 + r * 4;
            float4 v = *(const float4*)&wrow[kc * 64 + kk];
            Bs[kk + 0][ml] = v.x; Bs[kk + 1][ml] = v.y;
            Bs[kk + 2][ml] = v.z; Bs[kk + 3][ml] = v.w;
        }
        __syncthreads();
#pragma unroll 4
        for (int k = 0; k < 64; ++k) {
            float4 a4 = *(const float4*)&As[k][tm];
            float4 b4 = *(const float4*)&Bs[k][tg];
            float av[4] = {a4.x, a4.y, a4.z, a4.w};
            float bv[4] = {b4.x, b4.y, b4.z, b4.w};
#pragma unroll
            for (int i = 0; i < 4; ++i)
#pragma unroll
                for (int j = 0; j < 4; ++j)
                    acc[i][j] = fmaf(av[i], bv[j], acc[i][j]);
        }
        __syncthreads();
    }
    int m0 = bx * 64;
#pragma unroll
    for (int i = 0; i < 4; ++i) {
        int m = m0 + tm + i;
        float4 o;
        o.x = fmaxf(acc[i][0] + fc2_b[g0 + tg + 0], 0.f);
        o.y = fmaxf(acc[i][1] + fc2_b[g0 + tg + 1], 0.f);
        o.z = fmaxf(acc[i][2] + fc2_b[g0 + tg + 2], 0.f);
        o.w = fmaxf(acc[i][3] + fc2_b[g0 + tg + 3], 0.f);
        *(float4*)&logits[(size_t)m * Hn + g0 + tg] = o;
    }
}

// ==================================================================
// recur5: single cooperative kernel. 192 WGs x 512 thr, 34 KB LDS.
// Per WG: 16 rows (layer-clean). gemm_pass: A in LDS (broadcast b128),
// X chunks 16-deep, 2-generation reg pipeline (issue ~650cy before
// ds_write). Phases: {c2,h1,W2} | {c4,h2,W4} | {h3,h4} | 63x main.
// 66 grid.syncs total.
// ==================================================================
template<int NC>
__device__ __forceinline__ void gemm_pass(
        const float* __restrict__ A, int row0,
        const float* __restrict__ Bp, int bstride,
        float* __restrict__ dst, int dstride, int dcol0,
        const float* __restrict__ addRow, int tid,
        float* __restrict__ AsF, float* __restrict__ XsF) {
    constexpr int NF4 = NC / 4;
    constexpr int TOT4 = 16 * NF4;
    constexpr int PFN = (TOT4 + 511) / 512;
    const int cq = tid & 127;
    const int rq = tid >> 7;
    const bool cact = (2 * cq < NC);
    const int arow = tid & 15, akq = tid >> 4;
    const bool aact = (tid < 64);

    float acc[4][2] = {};
    float4 pxA[PFN], pxB[PFN], paA = {}, paB = {};

    auto loadX = [&](int c, float4* px) {
#pragma unroll
        for (int i = 0; i < PFN; ++i) {
            int e = tid + i * 512;
            if ((TOT4 % 512 == 0) || e < TOT4) {
                int k = e / NF4, c4 = (e % NF4) * 4;
                px[i] = *(const float4*)(Bp + (size_t)(c * 16 + k) * bstride + c4);
            }
        }
    };
    auto writeX = [&](int c, const float4* px) {
#pragma unroll
        for (int i = 0; i < PFN; ++i) {
            int e = tid + i * 512;
            if ((TOT4 % 512 == 0) || e < TOT4) {
                int k = e / NF4, c4 = (e % NF4) * 4;
                *(float4*)&XsF[(size_t)(c & 1) * 4096 + k * 256 + c4] = px[i];
            }
        }
    };
    auto loadA = [&](int c) -> float4 {
        return *(const float4*)(A + (size_t)(row0 + arow) * 1024 + c * 16 + akq * 4);
    };
    auto writeA = [&](int c, float4 pa) {
        float* base = &AsF[(size_t)(c & 1) * 256 + arow];
        base[(akq * 4 + 0) * 16] = pa.x;
        base[(akq * 4 + 1) * 16] = pa.y;
        base[(akq * 4 + 2) * 16] = pa.z;
        base[(akq * 4 + 3) * 16] = pa.w;
    };
    auto compute = [&](int c) {
        if (!cact) return;
        const float* xsc = &XsF[(size_t)(c & 1) * 4096 + 2 * cq];
        const float* asc = &AsF[(size_t)(c & 1) * 256 + rq * 4];
#pragma unroll
        for (int kk = 0; kk < 16; ++kk) {
            float4 a4 = *(const float4*)(asc + kk * 16);   // wave-uniform broadcast
            float2 x2 = *(const float2*)(xsc + kk * 256);
            acc[0][0] = fmaf(a4.x, x2.x, acc[0][0]);
            acc[0][1] = fmaf(a4.x, x2.y, acc[0][1]);
            acc[1][0] = fmaf(a4.y, x2.x, acc[1][0]);
            acc[1][1] = fmaf(a4.y, x2.y, acc[1][1]);
            acc[2][0] = fmaf(a4.z, x2.x, acc[2][0]);
            acc[2][1] = fmaf(a4.z, x2.y, acc[2][1]);
            acc[3][0] = fmaf(a4.w, x2.x, acc[3][0]);
            acc[3][1] = fmaf(a4.w, x2.y, acc[3][1]);
        }
    };

    loadX(0, pxA); if (aact) paA = loadA(0);
    loadX(1, pxB); if (aact) paB = loadA(1);
    writeX(0, pxA); if (aact) writeA(0, paA);
    __syncthreads();
    for (int c2i = 0; c2i < 32; ++c2i) {
        const int ck = 2 * c2i;
        // even chunk
        if (ck + 2 < 64) { loadX(ck + 2, pxA); if (aact) paA = loadA(ck + 2); }
        compute(ck);
        writeX(ck + 1, pxB); if (aact) writeA(ck + 1, paB);
        __syncthreads();
        // odd chunk
        if (ck + 3 < 64) { loadX(ck + 3, pxB); if (aact) paB = loadA(ck + 3); }
        compute(ck + 1);
        if (ck + 2 < 64) {
            writeX(ck + 2, pxA); if (aact) writeA(ck + 2, paA);
            __syncthreads();
        }
    }
    if (cact) {
#pragma unroll
        for (int i = 0; i < 4; ++i) {
            int r = row0 + rq * 4 + i;
            float av = addRow ? addRow[r] : 0.0f;
            *(float2*)(dst + (size_t)r * dstride + dcol0 + 2 * cq) =
                make_float2(acc[i][0] + av, acc[i][1] + av);
        }
    }
    __syncthreads();   // protect LDS reuse by the next pass
}

// cvec16: outv[row0+r] = sum_k A[row0+r][k]*vec[k] + addv[row0+r]
__device__ __forceinline__ void cvec16(const float* __restrict__ A, int row0,
                                       const float* __restrict__ vec,
                                       const float* __restrict__ addv,
                                       float* __restrict__ outv, int tid) {
    int r = tid >> 5;        // 0..15
    int seg = tid & 31;
    const float* ar = A + (size_t)(row0 + r) * Hn;
    float s = 0.f;
#pragma unroll 8
    for (int j = 0; j < 32; ++j) s = fmaf(ar[seg + j * 32], vec[seg + j * 32], s);
    s += __shfl_xor(s, 1);  s += __shfl_xor(s, 2);  s += __shfl_xor(s, 4);
    s += __shfl_xor(s, 8);  s += __shfl_xor(s, 16);
    if (seg == 0) outv[row0 + r] = s + addv[row0 + r];
}

// fold batch s: tb[t] = tanh(h2+tanh(h1+tanh(h0+tb[t]))) for 4 timesteps
__device__ __forceinline__ void fold4(int s, const float* __restrict__ Xf,
                                      __hip_bfloat16* __restrict__ tb, int wg, int tid) {
    for (int e = wg * 512 + tid; e < 4 * Hn * Bn; e += 192 * 512) {
        int b = e & 63, g = (e >> 6) & 1023, tp = e >> 16;
        int c = tp * 64 + b;
        size_t tix = ((size_t)(4 * s + tp) * Hn + g) * 64 + b;
        float tv = __bfloat162float(tb[tix]);
        tv = tanhf(Xf[(size_t)g * 256 + c] + tv);
        tv = tanhf(Xf[262144 + (size_t)g * 256 + c] + tv);
        tv = tanhf(Xf[524288 + (size_t)g * 256 + c] + tv);
        tb[tix] = __float2bfloat16(tv);
    }
}

__global__ __launch_bounds__(512, 2) void recur5_kernel(
        const float* __restrict__ lin_w, const float* __restrict__ lin_b,
        const float* __restrict__ h0T, __hip_bfloat16* __restrict__ tb,
        float* __restrict__ w2, float* __restrict__ w4,
        float* __restrict__ c2g, float* __restrict__ c4g,
        float* __restrict__ X0, float* __restrict__ X1) {
    __shared__ __align__(16) float AsF[512];     // 2 x 16 x 16
    __shared__ __align__(16) float XsF[8192];    // 2 x 16 x 256
    const int tid = threadIdx.x;
    const int w = blockIdx.x;
    const int row0 = w * 16;
    const int l = row0 >> 10;
    cg::grid_group grid = cg::this_grid();

    // ---- Phase 0: c2 = Wb+b ; h1 = W h0 + b ; W2 = W*W ----
    cvec16(lin_w, row0, lin_b + l * Hn, lin_b, c2g, tid);
    gemm_pass<64>(lin_w, row0, h0T + (size_t)l * 65536, 64,
                  X0, 256, 0, lin_b, tid, AsF, XsF);
    for (int p = 0; p < 4; ++p)
        gemm_pass<256>(lin_w, row0, lin_w + (size_t)l * 1048576 + p * 256, 1024,
                       w2, 1024, p * 256, nullptr, tid, AsF, XsF);
    grid.sync();

    // ---- Phase 1: c4 = W2 c2 + c2 ; h2 = W2 h0 + c2 ; W4 = W2*W2 ----
    cvec16(w2, row0, c2g + l * Hn, c2g, c4g, tid);
    gemm_pass<64>(w2, row0, h0T + (size_t)l * 65536, 64,
                  X0, 256, 64, c2g, tid, AsF, XsF);
    for (int p = 0; p < 4; ++p)
        gemm_pass<256>(w2, row0, w2 + (size_t)l * 1048576 + p * 256, 1024,
                       w4, 1024, p * 256, nullptr, tid, AsF, XsF);
    grid.sync();

    // ---- Phase 2: h3 = W2 h1 + c2 ; h4 = W4 h0 + c4 ----
    gemm_pass<64>(w2, row0, X0 + (size_t)l * 262144, 256,
                  X0, 256, 128, c2g, tid, AsF, XsF);
    gemm_pass<64>(w4, row0, h0T + (size_t)l * 65536, 64,
                  X0, 256, 192, c4g, tid, AsF, XsF);
    grid.sync();

    // ---- Main: 63 supersteps + folds ----
    for (int s = 0; s < 63; ++s) {
        const float* Xin = (s & 1) ? X1 : X0;
        float* Xout = (s & 1) ? X0 : X1;
        fold4(s, Xin, tb, w, tid);
        gemm_pass<256>(w4, row0, Xin + (size_t)l * 262144, 256,
                       Xout, 256, 0, c4g, tid, AsF, XsF);
        grid.sync();
    }
    fold4(63, X1, tb, w, tid);
}

// ------------------------------------------------------------------
// softmax over each 1024-row of logits -> f32 out
// ------------------------------------------------------------------
__global__ __launch_bounds__(256) void softmax_kernel(const float* __restrict__ logits,
                                                      float* __restrict__ out) {
    __shared__ float redm[4];
    __shared__ float reds[4];
    __shared__ float bcast[2];
    int row = blockIdx.x, tid = threadIdx.x;
    const float* in = logits + (size_t)row * On;
    float4 v = *(const float4*)&in[tid * 4];
    float mx = fmaxf(fmaxf(v.x, v.y), fmaxf(v.z, v.w));
#pragma unroll
    for (int o = 32; o > 0; o >>= 1) mx = fmaxf(mx, __shfl_down(mx, o));
    if ((tid & 63) == 0) redm[tid >> 6] = mx;
    __syncthreads();
    if (tid == 0) bcast[0] = fmaxf(fmaxf(redm[0], redm[1]), fmaxf(redm[2], redm[3]));
    __syncthreads();
    float M = bcast[0];
    float e0 = expf(v.x - M), e1 = expf(v.y - M), e2 = expf(v.z - M), e3 = expf(v.w - M);
    float s = e0 + e1 + e2 + e3;
#pragma unroll
    for (int o = 32; o > 0; o >>= 1) s += __shfl_down(s, o);
    if ((tid & 63) == 0) reds[tid >> 6] = s;
    __syncthreads();
    if (tid == 0) bcast[1] = reds[0] + reds[1] + reds[2] + reds[3];
    __syncthreads();
    float inv = 1.0f / bcast[1];
    float4 o4 = make_float4(e0 * inv, e1 * inv, e2 * inv, e3 * inv);
    *(float4*)&out[(size_t)row * On + tid * 4] = o4;
}

// ------------------------------------------------------------------
extern "C" void kernel_launch(void* const* d_in, const int* in_sizes, int n_in,
                              void* d_out, int out_size, void* d_ws, size_t ws_size,
                              hipStream_t stream) {
    const float* x     = (const float*)d_in[0];
    const float* hid   = (const float*)d_in[1];
    const float* fc1_w = (const float*)d_in[2];
    const float* fc1_b = (const float*)d_in[3];
    const float* fc2_w = (const float*)d_in[4];
    const float* fc2_b = (const float*)d_in[5];
    const float* lin_w = (const float*)d_in[6];
    const float* lin_b = (const float*)d_in[7];
    float* out = (float*)d_out;

    char* wsb = (char*)d_ws;
    __hip_bfloat16* tb = (__hip_bfloat16*)wsb;            // 32 MB  [t][g][b]
    float* logits = (float*)(wsb + 33554432ull);          // 64 MB
    float* w2     = (float*)(wsb + 100663296ull);         // 12 MB [3072][1024]
    float* w4     = (float*)(wsb + 113246208ull);         // 12 MB
    float* X      = (float*)(wsb + 125829120ull);         // 2 x 3 MB [l][g][256]
    float* c2     = (float*)(wsb + 132120576ull);         // 12 KB
    float* c4     = (float*)(wsb + 132132864ull);         // 12 KB
    float* h0T    = (float*)(wsb + 132145152ull);         // 768 KB [l][k][64]
    float* h0proj = (float*)(wsb + 132931584ull);         // 256 KB

    float* X0 = X;
    float* X1 = X + 786432;

    prep_kernel<<<48, 256, 0, stream>>>(hid, h0T);
    g1_kernel<<<Bn, 256, 0, stream>>>(hid, fc1_w, fc1_b, h0proj);
    g2_kernel<<<dim3(Sn, Hn / 64), 256, 0, stream>>>(x, fc1_w, h0proj, tb);

    void* args[] = { (void*)&lin_w, (void*)&lin_b, (void*)&h0T, (void*)&tb,
                     (void*)&w2, (void*)&w4, (void*)&c2, (void*)&c4,
                     (void*)&X0, (void*)&X1 };
    hipLaunchCooperativeKernel((const void*)recur5_kernel, dim3(192), dim3(512),
                               args, 0, stream);

    g3_kernel<<<dim3(Sn, Hn / 64), 256, 0, stream>>>(tb, fc2_w, fc2_b, logits);
    softmax_kernel<<<Sn * Bn, 256, 0, stream>>>(logits, out);
}

// Round 11
// 6169.844 us; speedup vs baseline: 1.6116x; 1.6116x over previous
//
#include <hip/hip_runtime.h>
#include <hip/hip_bf16.h>

#define Bn 64
#define Sn 256
#define Cn 512
#define Hn 1024
#define On 1024
#define NL 3

typedef __attribute__((ext_vector_type(8))) short bf16x8;
typedef __attribute__((ext_vector_type(4))) float f32x4;

__device__ __forceinline__ ushort f2bf(float x) {
    __hip_bfloat16 b = __float2bfloat16(x);
    return *(ushort*)&b;
}
__device__ __forceinline__ float bf2f(ushort u) {
    __hip_bfloat16 b = *(__hip_bfloat16*)&u;
    return __bfloat162float(b);
}

// ------------------------------------------------------------------
// prep: h0T[l][k][b] = hid[b][l+1][k]
// ------------------------------------------------------------------
__global__ __launch_bounds__(256) void prep_kernel(const float* __restrict__ hid,
                                                   float* __restrict__ h0T) {
    __shared__ float T[64][65];
    int l = blockIdx.x >> 4;
    int kb = (blockIdx.x & 15) * 64;
    int tid = threadIdx.x;
    for (int e = tid; e < 1024; e += 256) {
        int b = e >> 4, k4 = (e & 15) * 4;
        float4 v = *(const float4*)&hid[(size_t)b * 4096 + (size_t)(l + 1) * 1024 + kb + k4];
        T[b][k4] = v.x; T[b][k4 + 1] = v.y; T[b][k4 + 2] = v.z; T[b][k4 + 3] = v.w;
    }
    __syncthreads();
    for (int e = tid; e < 1024; e += 256) {
        int k = e >> 4, b4 = (e & 15) * 4;
        float4 v = make_float4(T[b4][k], T[b4 + 1][k], T[b4 + 2][k], T[b4 + 3][k]);
        *(float4*)&h0T[(size_t)l * 65536 + (size_t)(kb + k) * 64 + b4] = v;
    }
}

// ------------------------------------------------------------------
// G1
// ------------------------------------------------------------------
__global__ __launch_bounds__(256) void g1_kernel(const float* __restrict__ hid,
                                                 const float* __restrict__ fc1_w,
                                                 const float* __restrict__ fc1_b,
                                                 float* __restrict__ h0proj) {
    __shared__ __align__(16) float h0s[Hn];
    int b = blockIdx.x;
    int tid = threadIdx.x;
    for (int i = tid; i < Hn; i += 256) h0s[i] = hid[(size_t)b * 4 * Hn + i];
    __syncthreads();
    for (int g = tid; g < Hn; g += 256) {
        const float* wr = fc1_w + (size_t)g * (Cn + Hn) + Cn;
        float acc = 0.f;
        for (int k = 0; k < Hn; k += 4) {
            float4 w4 = *(const float4*)&wr[k];
            acc = fmaf(w4.x, h0s[k + 0], acc);
            acc = fmaf(w4.y, h0s[k + 1], acc);
            acc = fmaf(w4.z, h0s[k + 2], acc);
            acc = fmaf(w4.w, h0s[k + 3], acc);
        }
        h0proj[b * Hn + g] = acc + fc1_b[g];
    }
}

// ------------------------------------------------------------------
// G2
// ------------------------------------------------------------------
__global__ __launch_bounds__(256) void g2_kernel(const float* __restrict__ x,
                                                 const float* __restrict__ fc1_w,
                                                 const float* __restrict__ h0proj,
                                                 __hip_bfloat16* __restrict__ tb) {
    __shared__ __align__(16) float As[64][64];
    __shared__ __align__(16) float Bs[64][64];
    int tid = threadIdx.x;
    int bx = blockIdx.x;
    int g0 = blockIdx.y * 64;
    int ml = tid & 63;
    int kq = tid >> 6;
    const float* xrow = x + (size_t)ml * (Sn * Cn) + (size_t)bx * Cn;
    const float* wrow = fc1_w + (size_t)(g0 + ml) * (Cn + Hn);
    int wave = tid >> 6, lane = tid & 63;
    int tm = (wave & 1) * 32 + (lane & 7) * 4;
    int tg = (wave >> 1) * 32 + (lane >> 3) * 4;
    float acc[4][4] = {};
    for (int kc = 0; kc < Cn / 64; ++kc) {
#pragma unroll
        for (int r = 0; r < 4; ++r) {
            int kk = kq * 16 + r * 4;
            float4 v = *(const float4*)&xrow[kc * 64 + kk];
            As[kk + 0][ml] = v.x; As[kk + 1][ml] = v.y;
            As[kk + 2][ml] = v.z; As[kk + 3][ml] = v.w;
        }
#pragma unroll
        for (int r = 0; r < 4; ++r) {
            int kk = kq * 16 + r * 4;
            float4 v = *(const float4*)&wrow[kc * 64 + kk];
            Bs[kk + 0][ml] = v.x; Bs[kk + 1][ml] = v.y;
            Bs[kk + 2][ml] = v.z; Bs[kk + 3][ml] = v.w;
        }
        __syncthreads();
#pragma unroll 4
        for (int k = 0; k < 64; ++k) {
            float4 a4 = *(const float4*)&As[k][tm];
            float4 b4 = *(const float4*)&Bs[k][tg];
            float av[4] = {a4.x, a4.y, a4.z, a4.w};
            float bv[4] = {b4.x, b4.y, b4.z, b4.w};
#pragma unroll
            for (int i = 0; i < 4; ++i)
#pragma unroll
                for (int j = 0; j < 4; ++j)
                    acc[i][j] = fmaf(av[i], bv[j], acc[i][j]);
        }
        __syncthreads();
    }
#pragma unroll
    for (int j = 0; j < 4; ++j) {
        int g = g0 + tg + j;
        union { ushort4 u4; __hip_bfloat16 h[4]; } cv;
#pragma unroll
        for (int i = 0; i < 4; ++i) {
            float hp = h0proj[(size_t)(tm + i) * Hn + g];
            cv.h[i] = __float2bfloat16(tanhf(acc[i][j] + hp));
        }
        *(ushort4*)&tb[((size_t)bx * Hn + g) * 64 + tm] = cv.u4;
    }
}

// ------------------------------------------------------------------
// G3
// ------------------------------------------------------------------
__global__ __launch_bounds__(256) void g3_kernel(const __hip_bfloat16* __restrict__ tb,
                                                 const float* __restrict__ fc2_w,
                                                 const float* __restrict__ fc2_b,
                                                 float* __restrict__ logits) {
    __shared__ __align__(16) float As[64][64];
    __shared__ __align__(16) float Bs[64][64];
    int tid = threadIdx.x;
    int bx = blockIdx.x;
    int g0 = blockIdx.y * 64;
    int ml = tid & 63;
    int kq = tid >> 6;
    const float* wrow = fc2_w + (size_t)(g0 + ml) * Hn;
    int wave = tid >> 6, lane = tid & 63;
    int tm = (wave & 1) * 32 + (lane & 7) * 4;
    int tg = (wave >> 1) * 32 + (lane >> 3) * 4;
    float acc[4][4] = {};
    for (int kc = 0; kc < Hn / 64; ++kc) {
        for (int e = tid; e < 4096; e += 256) {
            int kk = e >> 6, mm = e & 63;
            As[kk][mm] = __bfloat162float(tb[((size_t)bx * Hn + kc * 64 + kk) * 64 + mm]);
        }
#pragma unroll
        for (int r = 0; r < 4; ++r) {
            int kk = kq * 16 + r * 4;
            float4 v = *(const float4*)&wrow[kc * 64 + kk];
            Bs[kk + 0][ml] = v.x; Bs[kk + 1][ml] = v.y;
            Bs[kk + 2][ml] = v.z; Bs[kk + 3][ml] = v.w;
        }
        __syncthreads();
#pragma unroll 4
        for (int k = 0; k < 64; ++k) {
            float4 a4 = *(const float4*)&As[k][tm];
            float4 b4 = *(const float4*)&Bs[k][tg];
            float av[4] = {a4.x, a4.y, a4.z, a4.w};
            float bv[4] = {b4.x, b4.y, b4.z, b4.w};
#pragma unroll
            for (int i = 0; i < 4; ++i)
#pragma unroll
                for (int j = 0; j < 4; ++j)
                    acc[i][j] = fmaf(av[i], bv[j], acc[i][j]);
        }
        __syncthreads();
    }
    int m0 = bx * 64;
#pragma unroll
    for (int i = 0; i < 4; ++i) {
        int m = m0 + tm + i;
        float4 o;
        o.x = fmaxf(acc[i][0] + fc2_b[g0 + tg + 0], 0.f);
        o.y = fmaxf(acc[i][1] + fc2_b[g0 + tg + 1], 0.f);
        o.z = fmaxf(acc[i][2] + fc2_b[g0 + tg + 2], 0.f);
        o.w = fmaxf(acc[i][3] + fc2_b[g0 + tg + 3], 0.f);
        *(float4*)&logits[(size_t)m * Hn + g0 + tg] = o;
    }
}

// ------------------------------------------------------------------
// cvec
// ------------------------------------------------------------------
__global__ __launch_bounds__(256) void cvec_kernel(const float* __restrict__ A,
                                                   const float* __restrict__ vecB,
                                                   const float* __restrict__ addB,
                                                   float* __restrict__ outv) {
    int row = blockIdx.x * 4 + (threadIdx.x >> 6);
    int lane = threadIdx.x & 63;
    int l = row >> 10;
    const float* ar = A + (size_t)row * Hn;
    const float* vb = vecB + (size_t)l * Hn;
    float s = 0.f;
#pragma unroll 4
    for (int j = 0; j < 16; ++j) {
        int k = lane + j * 64;
        s = fmaf(ar[k], vb[k], s);
    }
    s += __shfl_xor(s, 1);  s += __shfl_xor(s, 2);  s += __shfl_xor(s, 4);
    s += __shfl_xor(s, 8);  s += __shfl_xor(s, 16); s += __shfl_xor(s, 32);
    if (lane == 0) outv[row] = s + addB[row];
}

// ==================================================================
// gsl4<NC>: f32 GEMM (r9-proven) for prologue: W2, W4, seeds.
// ==================================================================
template<int NC>
__global__ __launch_bounds__(512, 2) void gsl4_kernel(
        const float* __restrict__ A, const float* __restrict__ Bsrc,
        unsigned long long bPanel, int bstride, int bcol0,
        float* __restrict__ dst, int dstride, int dcol0,
        const float* __restrict__ addRow) {
    __shared__ __align__(16) float As[2][16][16];
    __shared__ __align__(16) float Xs[2][16][NC];
    const int tid = threadIdx.x;
    const int wg = blockIdx.x;
    const int row0 = wg * 16;
    const int l = row0 >> 10;
    const int cq = tid & 127;
    const int rq = tid >> 7;
    const float* __restrict__ Bp = Bsrc + (size_t)l * bPanel + bcol0;
    constexpr int NF4 = NC / 4;
    constexpr int TOT4 = 16 * NF4;
    constexpr int PFN = (TOT4 + 511) / 512;
    const bool cact = (2 * cq < NC);
    const int arow = tid & 15, akq = tid >> 4;
    const bool aact = (tid < 64);

    float acc[4][2] = {};
    float4 px[PFN];
    float4 pa;

#pragma unroll
    for (int i = 0; i < PFN; ++i) {
        int e = tid + i * 512;
        if ((TOT4 % 512 == 0) || e < TOT4) {
            int k = e / NF4, c4 = (e % NF4) * 4;
            px[i] = *(const float4*)(Bp + (size_t)k * bstride + c4);
        }
    }
    if (aact) pa = *(const float4*)(A + (size_t)(row0 + arow) * 1024 + akq * 4);
#pragma unroll
    for (int i = 0; i < PFN; ++i) {
        int e = tid + i * 512;
        if ((TOT4 % 512 == 0) || e < TOT4) {
            int k = e / NF4, c4 = (e % NF4) * 4;
            *(float4*)&Xs[0][k][c4] = px[i];
        }
    }
    if (aact) {
        As[0][akq * 4 + 0][arow] = pa.x;
        As[0][akq * 4 + 1][arow] = pa.y;
        As[0][akq * 4 + 2][arow] = pa.z;
        As[0][akq * 4 + 3][arow] = pa.w;
    }
    __syncthreads();

    for (int ck = 0; ck < 64; ++ck) {
        if (ck < 63) {
#pragma unroll
            for (int i = 0; i < PFN; ++i) {
                int e = tid + i * 512;
                if ((TOT4 % 512 == 0) || e < TOT4) {
                    int k = e / NF4, c4 = (e % NF4) * 4;
                    px[i] = *(const float4*)(Bp + (size_t)((ck + 1) * 16 + k) * bstride + c4);
                }
            }
            if (aact)
                pa = *(const float4*)(A + (size_t)(row0 + arow) * 1024 + (ck + 1) * 16 + akq * 4);
        }
        if (cact) {
            const float* xsc = &Xs[ck & 1][0][2 * cq];
            const float* asc = &As[ck & 1][0][rq * 4];
#pragma unroll
            for (int kk = 0; kk < 16; ++kk) {
                float4 a4 = *(const float4*)(asc + kk * 16);
                float2 x2 = *(const float2*)(xsc + kk * NC);
                acc[0][0] = fmaf(a4.x, x2.x, acc[0][0]);
                acc[0][1] = fmaf(a4.x, x2.y, acc[0][1]);
                acc[1][0] = fmaf(a4.y, x2.x, acc[1][0]);
                acc[1][1] = fmaf(a4.y, x2.y, acc[1][1]);
                acc[2][0] = fmaf(a4.z, x2.x, acc[2][0]);
                acc[2][1] = fmaf(a4.z, x2.y, acc[2][1]);
                acc[3][0] = fmaf(a4.w, x2.x, acc[3][0]);
                acc[3][1] = fmaf(a4.w, x2.y, acc[3][1]);
            }
        }
        if (ck < 63) {
#pragma unroll
            for (int i = 0; i < PFN; ++i) {
                int e = tid + i * 512;
                if ((TOT4 % 512 == 0) || e < TOT4) {
                    int k = e / NF4, c4 = (e % NF4) * 4;
                    *(float4*)&Xs[(ck + 1) & 1][k][c4] = px[i];
                }
            }
            if (aact) {
                As[(ck + 1) & 1][akq * 4 + 0][arow] = pa.x;
                As[(ck + 1) & 1][akq * 4 + 1][arow] = pa.y;
                As[(ck + 1) & 1][akq * 4 + 2][arow] = pa.z;
                As[(ck + 1) & 1][akq * 4 + 3][arow] = pa.w;
            }
            __syncthreads();
        }
    }

    if (cact) {
#pragma unroll
        for (int i = 0; i < 4; ++i) {
            int r = row0 + rq * 4 + i;
            float av = addRow ? addRow[r] : 0.0f;
            float2 o = make_float2(acc[i][0] + av, acc[i][1] + av);
            *(float2*)(dst + (size_t)r * dstride + dcol0 + 2 * cq) = o;
        }
    }
}

// ------------------------------------------------------------------
// wsplit: W4 f32 -> hi/lo bf16 (row-major)
// ------------------------------------------------------------------
__global__ __launch_bounds__(256) void wsplit_kernel(const float* __restrict__ w4,
                                                     ushort* __restrict__ whi,
                                                     ushort* __restrict__ wlo) {
    int i = blockIdx.x * 256 + threadIdx.x;       // float4 index, grid covers 786432
    float4 v = ((const float4*)w4)[i];
    ushort4 h, l;
    h.x = f2bf(v.x); l.x = f2bf(v.x - bf2f(h.x));
    h.y = f2bf(v.y); l.y = f2bf(v.y - bf2f(h.y));
    h.z = f2bf(v.z); l.z = f2bf(v.z - bf2f(h.z));
    h.w = f2bf(v.w); l.w = f2bf(v.w - bf2f(h.w));
    *(ushort4*)&whi[(size_t)i * 4] = h;
    *(ushort4*)&wlo[(size_t)i * 4] = l;
}

// ------------------------------------------------------------------
// xsplitT: X0 f32 [l][g][c] -> XThi/XTlo bf16 [l][c][k=g]
// ------------------------------------------------------------------
__global__ __launch_bounds__(256) void xsplitT_kernel(const float* __restrict__ X0,
                                                      ushort* __restrict__ xthi,
                                                      ushort* __restrict__ xtlo) {
    __shared__ float T[64][65];
    int bid = blockIdx.x;
    int l = bid >> 6;
    int rem = bid & 63;
    int gb = rem >> 2, cbk = rem & 3;
    int g0 = gb * 64, c0 = cbk * 64;
    int tid = threadIdx.x;
#pragma unroll
    for (int p = 0; p < 4; ++p) {
        int g = p * 16 + (tid >> 4);
        int c4 = (tid & 15) * 4;
        float4 v = *(const float4*)&X0[(size_t)l * 262144 + (size_t)(g0 + g) * 256 + c0 + c4];
        T[g][c4] = v.x; T[g][c4 + 1] = v.y; T[g][c4 + 2] = v.z; T[g][c4 + 3] = v.w;
    }
    __syncthreads();
#pragma unroll
    for (int p = 0; p < 4; ++p) {
        int c = p * 16 + (tid >> 4);
        int k4 = (tid & 15) * 4;
        ushort4 h, lo;
        float v0 = T[k4 + 0][c], v1 = T[k4 + 1][c], v2 = T[k4 + 2][c], v3 = T[k4 + 3][c];
        h.x = f2bf(v0); lo.x = f2bf(v0 - bf2f(h.x));
        h.y = f2bf(v1); lo.y = f2bf(v1 - bf2f(h.y));
        h.z = f2bf(v2); lo.z = f2bf(v2 - bf2f(h.z));
        h.w = f2bf(v3); lo.w = f2bf(v3 - bf2f(h.w));
        size_t off = (size_t)l * 262144 + (size_t)(c0 + c) * 1024 + g0 + k4;
        *(ushort4*)&xthi[off] = h;
        *(ushort4*)&xtlo[off] = lo;
    }
}

// ==================================================================
// msl: MFMA superstep. grid (48,4) x 256 thr.
// C[64x64] = Whi*Bhi + Whi*Blo + Wlo*Bhi (f32 acc) + c4.
// LDS: 4 x [64][64] bf16 tiles, XOR-swizzled (G4), reg-prefetched.
// Head: fused fold of batch s (reads Xin f32).
// Epilogue: Xout f32 + split/transposed bf16 hi/lo for next step.
// ==================================================================
__global__ __launch_bounds__(256) void msl_kernel(
        const ushort* __restrict__ Whi, const ushort* __restrict__ Wlo,
        const ushort* __restrict__ BThi, const ushort* __restrict__ BTlo,
        const float* __restrict__ c4,
        const float* __restrict__ Xin, float* __restrict__ Xout,
        ushort* __restrict__ XThiOut, ushort* __restrict__ XTloOut,
        __hip_bfloat16* __restrict__ tb, int s) {
    __shared__ __align__(16) ushort Ah[4096];
    __shared__ __align__(16) ushort Al[4096];
    __shared__ __align__(16) ushort Bh[4096];
    __shared__ __align__(16) ushort Bl[4096];
    const int tid = threadIdx.x;
    const int rb = blockIdx.x;
    const int cb = blockIdx.y;
    const int row0 = rb * 64;
    const int col0 = cb * 64;
    const int l = rb >> 4;

    // ---- fused fold batch s ----
    {
        int wg = rb * 4 + cb;
        for (int e = wg * 256 + tid; e < 4 * Hn * Bn; e += 192 * 256) {
            int b = e & 63, g = (e >> 6) & 1023, tp = e >> 16;
            int c = tp * 64 + b;
            size_t tix = ((size_t)(4 * s + tp) * Hn + g) * 64 + b;
            float tv = __bfloat162float(tb[tix]);
            tv = tanhf(Xin[(size_t)g * 256 + c] + tv);
            tv = tanhf(Xin[262144 + (size_t)g * 256 + c] + tv);
            tv = tanhf(Xin[524288 + (size_t)g * 256 + c] + tv);
            tb[tix] = __float2bfloat16(tv);
        }
    }

    const int lane = tid & 63;
    const int w = tid >> 6;          // wave id = col tile
    const int fr = lane & 15;
    const int fq = lane >> 4;

    f32x4 acc[4];
#pragma unroll
    for (int i = 0; i < 4; ++i) acc[i] = (f32x4){0.f, 0.f, 0.f, 0.f};

    const int srow = tid >> 3;       // 0..31
    const int sk16 = (tid & 7) * 8;  // bf16 units

    const ushort* Ahsrc = Whi + (size_t)row0 * 1024;
    const ushort* Alsrc = Wlo + (size_t)row0 * 1024;
    const ushort* Bhsrc = BThi + (size_t)l * 262144 + (size_t)col0 * 1024;
    const ushort* Blsrc = BTlo + (size_t)l * 262144 + (size_t)col0 * 1024;

    float4 pf0[4], pf1[4];

    auto issue = [&](int k0) {
        size_t g0o = (size_t)srow * 1024 + k0 + sk16;
        size_t g1o = (size_t)(srow + 32) * 1024 + k0 + sk16;
        pf0[0] = *(const float4*)(Ahsrc + g0o);
        pf0[1] = *(const float4*)(Alsrc + g0o);
        pf0[2] = *(const float4*)(Bhsrc + g0o);
        pf0[3] = *(const float4*)(Blsrc + g0o);
        pf1[0] = *(const float4*)(Ahsrc + g1o);
        pf1[1] = *(const float4*)(Alsrc + g1o);
        pf1[2] = *(const float4*)(Bhsrc + g1o);
        pf1[3] = *(const float4*)(Blsrc + g1o);
    };
    auto commit = [&]() {
        int off0 = srow * 64 + (sk16 ^ ((srow & 7) << 3));
        int off1 = (srow + 32) * 64 + (sk16 ^ (((srow + 32) & 7) << 3));
        *(float4*)(Ah + off0) = pf0[0];
        *(float4*)(Al + off0) = pf0[1];
        *(float4*)(Bh + off0) = pf0[2];
        *(float4*)(Bl + off0) = pf0[3];
        *(float4*)(Ah + off1) = pf1[0];
        *(float4*)(Al + off1) = pf1[1];
        *(float4*)(Bh + off1) = pf1[2];
        *(float4*)(Bl + off1) = pf1[3];
    };

    issue(0);
    commit();
    __syncthreads();
    for (int ck = 0; ck < 16; ++ck) {
        if (ck < 15) issue((ck + 1) * 64);
#pragma unroll
        for (int ks = 0; ks < 2; ++ks) {
            int k16 = ks * 32 + fq * 8;
            int bro = w * 16 + fr;
            int boff = bro * 64 + (k16 ^ ((bro & 7) << 3));
            bf16x8 bhf = *(const bf16x8*)(Bh + boff);
            bf16x8 blf = *(const bf16x8*)(Bl + boff);
#pragma unroll
            for (int rt = 0; rt < 4; ++rt) {
                int aro = rt * 16 + fr;
                int aoff = aro * 64 + (k16 ^ ((aro & 7) << 3));
                bf16x8 ahf = *(const bf16x8*)(Ah + aoff);
                bf16x8 alf = *(const bf16x8*)(Al + aoff);
                acc[rt] = __builtin_amdgcn_mfma_f32_16x16x32_bf16(ahf, bhf, acc[rt], 0, 0, 0);
                acc[rt] = __builtin_amdgcn_mfma_f32_16x16x32_bf16(ahf, blf, acc[rt], 0, 0, 0);
                acc[rt] = __builtin_amdgcn_mfma_f32_16x16x32_bf16(alf, bhf, acc[rt], 0, 0, 0);
            }
        }
        __syncthreads();
        if (ck < 15) {
            commit();
            __syncthreads();
        }
    }

    // ---- epilogue: bias, f32 X, split/transposed bf16 ----
    int cg = col0 + w * 16 + fr;
#pragma unroll
    for (int rt = 0; rt < 4; ++rt) {
        int rbase = row0 + rt * 16 + fq * 4;
        float hv[4];
        ushort hi[4], lo[4];
#pragma unroll
        for (int r = 0; r < 4; ++r) {
            hv[r] = acc[rt][r] + c4[rbase + r];
            Xout[(size_t)(rbase + r) * 256 + cg] = hv[r];
            hi[r] = f2bf(hv[r]);
            lo[r] = f2bf(hv[r] - bf2f(hi[r]));
        }
        int rloc = rbase - l * 1024;
        size_t toff = (size_t)l * 262144 + (size_t)cg * 1024 + rloc;
        *(ushort4*)&XThiOut[toff] = make_ushort4(hi[0], hi[1], hi[2], hi[3]);
        *(ushort4*)&XTloOut[toff] = make_ushort4(lo[0], lo[1], lo[2], lo[3]);
    }
}

// ------------------------------------------------------------------
// standalone fold (batch 63)
// ------------------------------------------------------------------
__global__ __launch_bounds__(256) void foldb_kernel(const float* __restrict__ Xf,
                                                    __hip_bfloat16* __restrict__ tb, int s) {
    for (int e = blockIdx.x * 256 + threadIdx.x; e < 4 * Hn * Bn; e += gridDim.x * 256) {
        int b = e & 63, g = (e >> 6) & 1023, tp = e >> 16;
        int c = tp * 64 + b;
        size_t tix = ((size_t)(4 * s + tp) * Hn + g) * 64 + b;
        float tv = __bfloat162float(tb[tix]);
        tv = tanhf(Xf[(size_t)g * 256 + c] + tv);
        tv = tanhf(Xf[262144 + (size_t)g * 256 + c] + tv);
        tv = tanhf(Xf[524288 + (size_t)g * 256 + c] + tv);
        tb[tix] = __float2bfloat16(tv);
    }
}

// ------------------------------------------------------------------
// softmax
// ------------------------------------------------------------------
__global__ __launch_bounds__(256) void softmax_kernel(const float* __restrict__ logits,
                                                      float* __restrict__ out) {
    __shared__ float redm[4];
    __shared__ float reds[4];
    __shared__ float bcast[2];
    int row = blockIdx.x, tid = threadIdx.x;
    const float* in = logits + (size_t)row * On;
    float4 v = *(const float4*)&in[tid * 4];
    float mx = fmaxf(fmaxf(v.x, v.y), fmaxf(v.z, v.w));
#pragma unroll
    for (int o = 32; o > 0; o >>= 1) mx = fmaxf(mx, __shfl_down(mx, o));
    if ((tid & 63) == 0) redm[tid >> 6] = mx;
    __syncthreads();
    if (tid == 0) bcast[0] = fmaxf(fmaxf(redm[0], redm[1]), fmaxf(redm[2], redm[3]));
    __syncthreads();
    float M = bcast[0];
    float e0 = expf(v.x - M), e1 = expf(v.y - M), e2 = expf(v.z - M), e3 = expf(v.w - M);
    float s = e0 + e1 + e2 + e3;
#pragma unroll
    for (int o = 32; o > 0; o >>= 1) s += __shfl_down(s, o);
    if ((tid & 63) == 0) reds[tid >> 6] = s;
    __syncthreads();
    if (tid == 0) bcast[1] = reds[0] + reds[1] + reds[2] + reds[3];
    __syncthreads();
    float inv = 1.0f / bcast[1];
    float4 o4 = make_float4(e0 * inv, e1 * inv, e2 * inv, e3 * inv);
    *(float4*)&out[(size_t)row * On + tid * 4] = o4;
}

// ------------------------------------------------------------------
extern "C" void kernel_launch(void* const* d_in, const int* in_sizes, int n_in,
                              void* d_out, int out_size, void* d_ws, size_t ws_size,
                              hipStream_t stream) {
    const float* x     = (const float*)d_in[0];
    const float* hid   = (const float*)d_in[1];
    const float* fc1_w = (const float*)d_in[2];
    const float* fc1_b = (const float*)d_in[3];
    const float* fc2_w = (const float*)d_in[4];
    const float* fc2_b = (const float*)d_in[5];
    const float* lin_w = (const float*)d_in[6];
    const float* lin_b = (const float*)d_in[7];
    float* out = (float*)d_out;

    char* wsb = (char*)d_ws;
    __hip_bfloat16* tb = (__hip_bfloat16*)wsb;              // 0..32MB
    // overlay region [32MB,96MB): recurrence bf16 buffers, then logits (after)
    ushort* W4hi  = (ushort*)(wsb + 33554432ull);           // 6 MB
    ushort* W4lo  = (ushort*)(wsb + 39845888ull);           // 6 MB
    ushort* XThi0 = (ushort*)(wsb + 46137344ull);           // 1.5 MB
    ushort* XTlo0 = (ushort*)(wsb + 47710208ull);
    ushort* XThi1 = (ushort*)(wsb + 49283072ull);
    ushort* XTlo1 = (ushort*)(wsb + 50855936ull);           // ..52.4MB
    float* logits = (float*)(wsb + 33554432ull);            // 64 MB (used after recurrence)
    float* w2     = (float*)(wsb + 100663296ull);           // 12 MB
    float* w4     = (float*)(wsb + 113246208ull);           // 12 MB
    float* X0     = (float*)(wsb + 125829120ull);           // 3 MB f32 [l][g][c]
    float* X1     = (float*)(wsb + 128974848ull);           // 3 MB
    float* c2     = (float*)(wsb + 132120576ull);           // 12 KB
    float* c4     = (float*)(wsb + 132132864ull);           // 12 KB
    float* h0T    = (float*)(wsb + 132145152ull);           // 768 KB
    float* h0proj = (float*)(wsb + 132931584ull);           // 256 KB

    prep_kernel<<<48, 256, 0, stream>>>(hid, h0T);
    g1_kernel<<<Bn, 256, 0, stream>>>(hid, fc1_w, fc1_b, h0proj);
    g2_kernel<<<dim3(Sn, Hn / 64), 256, 0, stream>>>(x, fc1_w, h0proj, tb);

    // ---- f32 prologue: powers, c-vectors, seeds ----
    cvec_kernel<<<768, 256, 0, stream>>>(lin_w, lin_b, lin_b, c2);
    for (int p = 0; p < 4; ++p)
        gsl4_kernel<256><<<192, 512, 0, stream>>>(lin_w, lin_w, 1048576ull, 1024, p * 256,
                                                  w2, 1024, p * 256, nullptr);
    cvec_kernel<<<768, 256, 0, stream>>>(w2, c2, c2, c4);
    for (int p = 0; p < 4; ++p)
        gsl4_kernel<256><<<192, 512, 0, stream>>>(w2, w2, 1048576ull, 1024, p * 256,
                                                  w4, 1024, p * 256, nullptr);
    gsl4_kernel<64><<<192, 512, 0, stream>>>(lin_w, h0T, 65536ull, 64, 0,
                                             X0, 256, 0, lin_b);
    gsl4_kernel<64><<<192, 512, 0, stream>>>(w2, h0T, 65536ull, 64, 0,
                                             X0, 256, 64, c2);
    gsl4_kernel<64><<<192, 512, 0, stream>>>(w4, h0T, 65536ull, 64, 0,
                                             X0, 256, 192, c4);
    gsl4_kernel<64><<<192, 512, 0, stream>>>(w2, X0, 262144ull, 256, 0,
                                             X0, 256, 128, c2);

    // ---- split W4 and seed X into bf16 hi/lo ----
    wsplit_kernel<<<3072, 256, 0, stream>>>(w4, W4hi, W4lo);
    xsplitT_kernel<<<192, 256, 0, stream>>>(X0, XThi0, XTlo0);

    // ---- main: 63 MFMA supersteps with fused folds ----
    for (int s = 0; s < 63; ++s) {
        const float* Xi = (s & 1) ? X1 : X0;
        float* Xo       = (s & 1) ? X0 : X1;
        const ushort* Bhi = (s & 1) ? XThi1 : XThi0;
        const ushort* Blo = (s & 1) ? XTlo1 : XTlo0;
        ushort* Bho = (s & 1) ? XThi0 : XThi1;
        ushort* Blo2 = (s & 1) ? XTlo0 : XTlo1;
        msl_kernel<<<dim3(48, 4), 256, 0, stream>>>(W4hi, W4lo, Bhi, Blo, c4,
                                                    Xi, Xo, Bho, Blo2, tb, s);
    }
    foldb_kernel<<<512, 256, 0, stream>>>(X1, tb, 63);

    g3_kernel<<<dim3(Sn, Hn / 64), 256, 0, stream>>>(tb, fc2_w, fc2_b, logits);
    softmax_kernel<<<Sn * Bn, 256, 0, stream>>>(logits, out);
}